// Round 5
// baseline (312.744 us; speedup 1.0000x reference)
//
#include <hip/hip_runtime.h>

// Forward-fill: out[r,t] = att[r, last index <= t where wet==0], t=0 forced dry.
// wet is int32 (harness converts bool -> int32).
//
// Wave-persistent, batched-MLP version: each WAVE owns a WSEG-elem segment of
// one row. Outer loop processes 1024 elems: 8 independent dwordx4 loads for
// the NEXT 1024 elems are issued first (double-buffered, 128 B/lane in
// flight), then four register-resident 256-elem ballot chains run. Carry is
// chained via one __shfl from lane 63 per chunk. No LDS, no __syncthreads.
// Segment carry-in comes from a backward ballot-search over preceding wet
// words (expected ~1 iter for random data; terminates at forced-dry t=0).

constexpr int BATCH  = 4;                 // chunks per outer iteration
constexpr int WCHUNK = 256;               // elems per chunk (64 lanes x 4)
constexpr int OBLK   = BATCH * WCHUNK;    // 1024 elems per outer iteration
constexpr int WSEG   = 8192;              // elems per wave segment
constexpr int OUTER  = WSEG / OBLK;       // 8

typedef float f4v __attribute__((ext_vector_type(4)));

__global__ __launch_bounds__(256) void ffill_wave_kernel(
    const float* __restrict__ att,
    const int* __restrict__ wet,
    float* __restrict__ out,
    int T, int segsPerRow)
{
    const int lane = threadIdx.x & 63;
    const int wid  = threadIdx.x >> 6;
    const int s    = blockIdx.x * 4 + wid;     // segment index within row
    if (s >= segsPerRow) return;               // wave-uniform exit
    const int r    = blockIdx.y;
    const long long rowBase = (long long)r * T;
    const int base = s * WSEG;

    // ---- backward lookback for the segment carry-in ----
    float carry = 0.0f;                        // unused for s==0 (t=0 forced dry)
    int hi = base;                             // exclusive upper bound
    while (hi > 0) {
        const int start = (hi >= 64) ? (hi - 64) : 0;
        const int idx   = start + lane;
        bool dry = false;
        if (idx < hi) dry = (wet[rowBase + idx] == 0) || (idx == 0);
        const unsigned long long m = __ballot(dry);
        if (m != 0ull) {
            carry = att[rowBase + start + (63 - __clzll(m))];
            break;
        }
        hi = start;
    }

    // ---- load batch 0 (8 independent dwordx4) ----
    float4 aC[BATCH]; int4 wC[BATCH];
    const int e0 = base + lane * 4;            // lane's elem in chunk 0
    #pragma unroll
    for (int k = 0; k < BATCH; ++k) {
        const int e = e0 + k * WCHUNK;
        if (e < T) {                           // T % 4 == 0 -> all-or-nothing per lane
            aC[k] = *reinterpret_cast<const float4*>(att + rowBase + e);
            wC[k] = *reinterpret_cast<const int4*>(wet + rowBase + e);
        } else {
            aC[k] = make_float4(0.f, 0.f, 0.f, 0.f);
            wC[k] = make_int4(1, 1, 1, 1);
        }
    }

    for (int ot = 0; ot < OUTER; ++ot) {
        // ---- prefetch next batch (in flight across all 4 ballot chains) ----
        float4 aN[BATCH]; int4 wN[BATCH];
        #pragma unroll
        for (int k = 0; k < BATCH; ++k) {
            aN[k] = make_float4(0.f, 0.f, 0.f, 0.f);
            wN[k] = make_int4(1, 1, 1, 1);
        }
        if (ot + 1 < OUTER) {
            const int eb = e0 + (ot + 1) * OBLK;
            #pragma unroll
            for (int k = 0; k < BATCH; ++k) {
                const int e = eb + k * WCHUNK;
                if (e < T) {
                    aN[k] = *reinterpret_cast<const float4*>(att + rowBase + e);
                    wN[k] = *reinterpret_cast<const int4*>(wet + rowBase + e);
                }
            }
        }

        // ---- process 4 register-resident chunks ----
        #pragma unroll
        for (int k = 0; k < BATCH; ++k) {
            const int e = e0 + ot * OBLK + k * WCHUNK;
            const bool valid = (e < T);

            bool d0 = (wC[k].x == 0) || (e == 0);   // forced dry at t=0
            bool d1 = (wC[k].y == 0);
            bool d2 = (wC[k].z == 0);
            bool d3 = (wC[k].w == 0);
            if (!valid) { d0 = d1 = d2 = d3 = false; }

            const bool has = d0 | d1 | d2 | d3;
            // value at the LAST dry position among this lane's 4 elements
            const float lastval = d3 ? aC[k].w : (d2 ? aC[k].z : (d1 ? aC[k].y : aC[k].x));

            // carry-in: rightmost dry among lower lanes, else wave carry
            const unsigned long long mask = __ballot(has);
            const unsigned long long pm = mask & ((1ull << lane) - 1ull);
            const int psrc = (pm != 0ull) ? (63 - __clzll(pm)) : 0;
            const float pval = __shfl(lastval, psrc);
            const float carry_in = (pm != 0ull) ? pval : carry;

            // sequential fill (computed for ALL lanes; invalid lanes keep carry_in)
            float running = carry_in;
            f4v o;
            running = d0 ? aC[k].x : running;  o.x = running;
            running = d1 ? aC[k].y : running;  o.y = running;
            running = d2 ? aC[k].z : running;  o.z = running;
            running = d3 ? aC[k].w : running;  o.w = running;
            if (valid) {
                __builtin_nontemporal_store(o, reinterpret_cast<f4v*>(out + rowBase + e));
            }

            // lane 63's running == fill value at the chunk's last element
            carry = __shfl(running, 63);
        }

        #pragma unroll
        for (int k = 0; k < BATCH; ++k) { aC[k] = aN[k]; wC[k] = wN[k]; }
    }
}

extern "C" void kernel_launch(void* const* d_in, const int* in_sizes, int n_in,
                              void* d_out, int out_size, void* d_ws, size_t ws_size,
                              hipStream_t stream) {
    const float* att = (const float*)d_in[0];
    const int* wet   = (const int*)d_in[1];
    float* out       = (float*)d_out;

    const int B = 64;
    const int T = in_sizes[0] / B;                      // 500000
    const int segsPerRow = (T + WSEG - 1) / WSEG;       // 62
    const int blocksX = (segsPerRow + 3) / 4;           // 4 waves per block -> 16

    dim3 grid(blocksX, B);
    dim3 block(256);
    ffill_wave_kernel<<<grid, block, 0, stream>>>(att, wet, out, T, segsPerRow);
}